// Round 2
// baseline (176.896 us; speedup 1.0000x reference)
//
#include <hip/hip_runtime.h>

#define NLEV 8
#define PTS_PER_BLOCK 32
#define ROW_F 51   // 3 + 6*NLEV

// ---------------------------------------------------------------------------
// Repack kernel: data (T anchors x 3 floats, packed) -> tab (T x float4, padded)
// Each thread handles 4 anchors: 3 aligned dwordx4 loads -> 4 dwordx4 stores.
// ---------------------------------------------------------------------------
__global__ __launch_bounds__(256) void repack_kernel(
    const float* __restrict__ data, float4* __restrict__ tab, int T)
{
    const int g = blockIdx.x * 256 + threadIdx.x;   // group of 4 anchors
    const int base = g * 4;
    if (base >= T) return;
    if (base + 4 <= T) {
        // base*3 floats = base*12 bytes = g*48 bytes -> 16B aligned
        const float4* src = (const float4*)(data + (size_t)base * 3);
        const float4 a = src[0], b = src[1], c = src[2];
        tab[base + 0] = make_float4(a.x, a.y, a.z, 0.f);
        tab[base + 1] = make_float4(a.w, b.x, b.y, 0.f);
        tab[base + 2] = make_float4(b.z, b.w, c.x, 0.f);
        tab[base + 3] = make_float4(c.y, c.z, c.w, 0.f);
    } else {
        for (int j = base; j < T; ++j)
            tab[j] = make_float4(data[3*(size_t)j], data[3*(size_t)j+1],
                                 data[3*(size_t)j+2], 0.f);
    }
}

// ---------------------------------------------------------------------------
// Main kernel, padded-table path: gather = 8 x global_load_dwordx4 per thread.
// ---------------------------------------------------------------------------
__global__ __launch_bounds__(256) void dagrid_kernel(
    const float* __restrict__ xyz,
    const float4* __restrict__ tab,
    const float* __restrict__ scales,
    const int*   __restrict__ level_offsets,
    const float* __restrict__ bounds,
    float* __restrict__ out,
    int npts)
{
    __shared__ alignas(16) float sxyz[PTS_PER_BLOCK * 3];
    __shared__ alignas(16) float sres[PTS_PER_BLOCK][ROW_F];

    const int tid = threadIdx.x;
    const int l   = tid & 7;        // level
    const int p   = tid >> 3;       // local point 0..31
    const int block_base = blockIdx.x * PTS_PER_BLOCK;
    const bool full_block = (block_base + PTS_PER_BLOCK <= npts);

    // coalesced stage of 32 points' xyz (vectorized when block fully in range)
    if (full_block) {
        if (tid < 24) {
            // block_base*3 floats = block_base*12 = blockIdx*384 bytes, 16B aligned
            ((float4*)sxyz)[tid] = ((const float4*)(xyz + (size_t)block_base * 3))[tid];
        }
    } else if (tid < PTS_PER_BLOCK * 3) {
        const int gi = block_base * 3 + tid;
        sxyz[tid] = (gi < npts * 3) ? xyz[gi] : 0.0f;
    }

    // per-level metadata (issued before the barrier, latency hides under sync)
    const float scale = scales[l];
    const int   off_l = level_offsets[l];

    const float lox = bounds[0], loy = bounds[1], loz = bounds[2];
    const float hix = bounds[3] - 1e-6f;
    const float hiy = bounds[4] - 1e-6f;
    const float hiz = bounds[5] - 1e-6f;
    const float size = fmaxf(fmaxf(bounds[3] - bounds[0], bounds[4] - bounds[1]),
                             bounds[5] - bounds[2]);
    const float inv_size = 1.0f / size;

    __syncthreads();

    const int n = block_base + p;
    const bool active = (n < npts);

    const float rx = sxyz[p * 3 + 0];
    const float ry = sxyz[p * 3 + 1];
    const float rz = sxyz[p * 3 + 2];

    float acc0 = 0.f, acc1 = 0.f, acc2 = 0.f, acc3 = 0.f, acc4 = 0.f, acc5 = 0.f;

    if (active) {
        const float x = fminf(fmaxf(rx, lox), hix);
        const float y = fminf(fmaxf(ry, loy), hiy);
        const float z = fminf(fmaxf(rz, loz), hiz);
        const float xn = (x - lox) * inv_size;
        const float yn = (y - loy) * inv_size;
        const float zn = (z - loz) * inv_size;

        const int r1   = (int)scale + 1;
        const int r1sq = r1 * r1;

        const float fx = xn * scale;
        const float fy = yn * scale;
        const float fz = zn * scale;
        const float bxf = floorf(fx), byf = floorf(fy), bzf = floorf(fz);
        const float ox = fx - bxf;
        const float oy = fy - byf;
        const float oz = fz - bzf;

        const int i000 = (int)bxf * r1sq + (int)byf * r1 + (int)bzf + off_l;

        // ---- gather: 4 corner z-pairs, 2 aligned dwordx4 each
        const float4* t0 = tab + i000;               // (0,0,z) (0,0,z+1)
        const float4* t1 = tab + i000 + r1;          // (0,1,*)
        const float4* t2 = tab + i000 + r1sq;        // (1,0,*)
        const float4* t3 = tab + i000 + r1sq + r1;   // (1,1,*)
        const float4 A0 = t0[0], B0 = t0[1];
        const float4 A1 = t1[0], B1 = t1[1];
        const float4 A2 = t2[0], B2 = t2[1];
        const float4 A3 = t3[0], B3 = t3[1];

        const float freq = (float)(1 << l);
        const float wz0  = 1.0f - oz;
        const float wx1 = ox, wx0 = 1.0f - ox;
        const float wy1 = oy, wy0 = 1.0f - oy;

        float sn, cs;
        #define PAIR(A, B, WXY)                                                   \
        {                                                                         \
            const float w0 = (WXY) * wz0;                                         \
            const float w1 = (WXY) * oz;                                          \
            __sincosf(A.x * freq, &sn, &cs); acc0 += w0 * sn; acc3 += w0 * cs;    \
            __sincosf(A.y * freq, &sn, &cs); acc1 += w0 * sn; acc4 += w0 * cs;    \
            __sincosf(A.z * freq, &sn, &cs); acc2 += w0 * sn; acc5 += w0 * cs;    \
            __sincosf(B.x * freq, &sn, &cs); acc0 += w1 * sn; acc3 += w1 * cs;    \
            __sincosf(B.y * freq, &sn, &cs); acc1 += w1 * sn; acc4 += w1 * cs;    \
            __sincosf(B.z * freq, &sn, &cs); acc2 += w1 * sn; acc5 += w1 * cs;    \
        }
        PAIR(A0, B0, wx0 * wy0)
        PAIR(A1, B1, wx0 * wy1)
        PAIR(A2, B2, wx1 * wy0)
        PAIR(A3, B3, wx1 * wy1)
        #undef PAIR
    }

    // stage results: row = [x, y, z, l0:6 feats, ...]
    {
        float* row = sres[p];
        const int c = 3 + l * 6;
        row[c + 0] = acc0; row[c + 1] = acc1; row[c + 2] = acc2;
        row[c + 3] = acc3; row[c + 4] = acc4; row[c + 5] = acc5;
        if (l == 0) { row[0] = rx; row[1] = ry; row[2] = rz; }
    }
    __syncthreads();

    // coalesced write: 32*51 = 1632 floats = 408 float4 per block (16B aligned)
    if (full_block) {
        const float4* flat4 = (const float4*)&sres[0][0];
        float4* ob4 = (float4*)(out + (size_t)block_base * ROW_F);
        for (int i = tid; i < (PTS_PER_BLOCK * ROW_F) / 4; i += 256)
            ob4[i] = flat4[i];
    } else {
        const float* flat = &sres[0][0];
        float* ob = out + (size_t)block_base * ROW_F;
        const int lim = npts * ROW_F - block_base * ROW_F;
        for (int i = tid; i < PTS_PER_BLOCK * ROW_F; i += 256)
            if (i < lim) ob[i] = flat[i];
    }
}

// ---------------------------------------------------------------------------
// Fallback (ws too small): previous direct-gather kernel, unchanged semantics.
// ---------------------------------------------------------------------------
__global__ __launch_bounds__(256) void dagrid_kernel_direct(
    const float* __restrict__ xyz,
    const float* __restrict__ data,
    const float* __restrict__ scales,
    const int*   __restrict__ level_offsets,
    const float* __restrict__ bounds,
    float* __restrict__ out,
    int npts)
{
    __shared__ float sxyz[PTS_PER_BLOCK * 3];
    __shared__ float sres[PTS_PER_BLOCK][ROW_F];

    const int tid = threadIdx.x;
    const int l   = tid & 7;
    const int p   = tid >> 3;
    const int block_base = blockIdx.x * PTS_PER_BLOCK;

    if (tid < PTS_PER_BLOCK * 3) {
        int gi = block_base * 3 + tid;
        sxyz[tid] = (gi < npts * 3) ? xyz[gi] : 0.0f;
    }
    const float scale = scales[l];
    const int   off_l = level_offsets[l];
    const float lox = bounds[0], loy = bounds[1], loz = bounds[2];
    const float hix = bounds[3] - 1e-6f;
    const float hiy = bounds[4] - 1e-6f;
    const float hiz = bounds[5] - 1e-6f;
    const float size = fmaxf(fmaxf(bounds[3] - bounds[0], bounds[4] - bounds[1]),
                             bounds[5] - bounds[2]);
    const float inv_size = 1.0f / size;
    __syncthreads();

    const int n = block_base + p;
    const bool active = (n < npts);
    const float rx = sxyz[p * 3 + 0];
    const float ry = sxyz[p * 3 + 1];
    const float rz = sxyz[p * 3 + 2];
    float acc0 = 0.f, acc1 = 0.f, acc2 = 0.f, acc3 = 0.f, acc4 = 0.f, acc5 = 0.f;

    if (active) {
        const float x = fminf(fmaxf(rx, lox), hix);
        const float y = fminf(fmaxf(ry, loy), hiy);
        const float z = fminf(fmaxf(rz, loz), hiz);
        const float xn = (x - lox) * inv_size;
        const float yn = (y - loy) * inv_size;
        const float zn = (z - loz) * inv_size;
        const int r1 = (int)scale + 1;
        const int r1sq = r1 * r1;
        const float fx = xn * scale, fy = yn * scale, fz = zn * scale;
        const float bxf = floorf(fx), byf = floorf(fy), bzf = floorf(fz);
        const float ox = fx - bxf, oy = fy - byf, oz = fz - bzf;
        const int i000 = (int)bxf * r1sq + (int)byf * r1 + (int)bzf + off_l;
        const float freq = (float)(1 << l);
        const float w_z0 = 1.0f - oz;
        #pragma unroll
        for (int cx = 0; cx < 2; ++cx) {
            const float wx = cx ? ox : (1.0f - ox);
            #pragma unroll
            for (int cy = 0; cy < 2; ++cy) {
                const float wxy = wx * (cy ? oy : (1.0f - oy));
                const float w0 = wxy * w_z0;
                const float w1 = wxy * oz;
                const float* pv = data + 3 * (size_t)(i000 + cx * r1sq + cy * r1);
                float sn, cs, a;
                a = pv[0] * freq; __sincosf(a, &sn, &cs); acc0 += w0 * sn; acc3 += w0 * cs;
                a = pv[1] * freq; __sincosf(a, &sn, &cs); acc1 += w0 * sn; acc4 += w0 * cs;
                a = pv[2] * freq; __sincosf(a, &sn, &cs); acc2 += w0 * sn; acc5 += w0 * cs;
                a = pv[3] * freq; __sincosf(a, &sn, &cs); acc0 += w1 * sn; acc3 += w1 * cs;
                a = pv[4] * freq; __sincosf(a, &sn, &cs); acc1 += w1 * sn; acc4 += w1 * cs;
                a = pv[5] * freq; __sincosf(a, &sn, &cs); acc2 += w1 * sn; acc5 += w1 * cs;
            }
        }
    }
    {
        float* row = sres[p];
        const int c = 3 + l * 6;
        row[c + 0] = acc0; row[c + 1] = acc1; row[c + 2] = acc2;
        row[c + 3] = acc3; row[c + 4] = acc4; row[c + 5] = acc5;
        if (l == 0) { row[0] = rx; row[1] = ry; row[2] = rz; }
    }
    __syncthreads();
    {
        const float* flat = &sres[0][0];
        float* ob = out + (size_t)block_base * ROW_F;
        const int lim = npts * ROW_F - block_base * ROW_F;
        for (int i = tid; i < PTS_PER_BLOCK * ROW_F; i += 256)
            if (i < lim) ob[i] = flat[i];
    }
}

extern "C" void kernel_launch(void* const* d_in, const int* in_sizes, int n_in,
                              void* d_out, int out_size, void* d_ws, size_t ws_size,
                              hipStream_t stream) {
    const float* xyz           = (const float*)d_in[0];
    const float* data          = (const float*)d_in[1];
    const float* scales        = (const float*)d_in[2];
    const int*   level_offsets = (const int*)d_in[3];
    const float* bounds        = (const float*)d_in[4];
    float* out = (float*)d_out;

    const int npts = in_sizes[0] / 3;       // in_sizes counts elements
    const int T    = in_sizes[1] / 3;       // total anchors in the table
    const int nblocks = (npts + PTS_PER_BLOCK - 1) / PTS_PER_BLOCK;

    const size_t ws_needed = (size_t)T * sizeof(float4);
    if (d_ws != nullptr && ws_size >= ws_needed) {
        float4* tab = (float4*)d_ws;
        const int rgroups = (T + 3) / 4;
        const int rblocks = (rgroups + 255) / 256;
        repack_kernel<<<rblocks, 256, 0, stream>>>(data, tab, T);
        dagrid_kernel<<<nblocks, 256, 0, stream>>>(xyz, tab, scales, level_offsets,
                                                   bounds, out, npts);
    } else {
        dagrid_kernel_direct<<<nblocks, 256, 0, stream>>>(xyz, data, scales,
                                                          level_offsets, bounds,
                                                          out, npts);
    }
}

// Round 3
// 142.157 us; speedup vs baseline: 1.2444x; 1.2444x over previous
//
#include <hip/hip_runtime.h>

#define NLEV 8
#define PTS_PER_BLOCK 32
#define ROW_F 51   // 3 + 6*NLEV

// 4B-aligned vector types: the anchor table is packed float3, so a z-pair's
// 6 floats start at a 12B-multiple offset (only dword-aligned). gfx9+ global
// multi-dword loads need only dword alignment.
typedef float f4u __attribute__((ext_vector_type(4), aligned(4)));
typedef float f2u __attribute__((ext_vector_type(2), aligned(4)));

__global__ __launch_bounds__(256) void dagrid_kernel(
    const float* __restrict__ xyz,
    const float* __restrict__ data,
    const float* __restrict__ scales,
    const int*   __restrict__ level_offsets,
    const float* __restrict__ bounds,
    float* __restrict__ out,
    int npts)
{
    __shared__ alignas(16) float sxyz[PTS_PER_BLOCK * 3];
    __shared__ alignas(16) float sres[PTS_PER_BLOCK][ROW_F];

    const int tid = threadIdx.x;
    const int l   = tid & 7;        // level
    const int p   = tid >> 3;       // local point 0..31
    const int block_base = blockIdx.x * PTS_PER_BLOCK;
    const bool full_block = (block_base + PTS_PER_BLOCK <= npts);

    // coalesced stage of 32 points' xyz
    if (full_block) {
        if (tid < 24) {
            // block_base*3 floats = blockIdx*384 bytes -> 16B aligned
            ((float4*)sxyz)[tid] = ((const float4*)(xyz + (size_t)block_base * 3))[tid];
        }
    } else if (tid < PTS_PER_BLOCK * 3) {
        const int gi = block_base * 3 + tid;
        sxyz[tid] = (gi < npts * 3) ? xyz[gi] : 0.0f;
    }

    // per-level metadata (issued before the barrier; latency hides under sync)
    const float scale = scales[l];
    const int   off_l = level_offsets[l];

    const float lox = bounds[0], loy = bounds[1], loz = bounds[2];
    const float hix = bounds[3] - 1e-6f;
    const float hiy = bounds[4] - 1e-6f;
    const float hiz = bounds[5] - 1e-6f;
    const float size = fmaxf(fmaxf(bounds[3] - bounds[0], bounds[4] - bounds[1]),
                             bounds[5] - bounds[2]);
    const float inv_size = 1.0f / size;

    __syncthreads();

    const int n = block_base + p;
    const bool active = (n < npts);

    const float rx = sxyz[p * 3 + 0];
    const float ry = sxyz[p * 3 + 1];
    const float rz = sxyz[p * 3 + 2];

    float acc0 = 0.f, acc1 = 0.f, acc2 = 0.f, acc3 = 0.f, acc4 = 0.f, acc5 = 0.f;

    if (active) {
        const float x = fminf(fmaxf(rx, lox), hix);
        const float y = fminf(fmaxf(ry, loy), hiy);
        const float z = fminf(fmaxf(rz, loz), hiz);
        const float xn = (x - lox) * inv_size;
        const float yn = (y - loy) * inv_size;
        const float zn = (z - loz) * inv_size;

        const int r1   = (int)scale + 1;
        const int r1sq = r1 * r1;

        const float fx = xn * scale;
        const float fy = yn * scale;
        const float fz = zn * scale;
        const float bxf = floorf(fx), byf = floorf(fy), bzf = floorf(fz);
        const float ox = fx - bxf;
        const float oy = fy - byf;
        const float oz = fz - bzf;

        const int i000 = (int)bxf * r1sq + (int)byf * r1 + (int)bzf + off_l;

        // ---- gather: 4 corner z-pairs; each = 6 packed floats = x4 + x2
        // (24 scattered bytes per pair -- the minimum; no padding waste)
        const float* p0 = data + 3 * (size_t)i000;            // (0,0,z/z+1)
        const float* p1 = p0 + 3 * r1;                        // (0,1,*)
        const float* p2 = p0 + 3 * r1sq;                      // (1,0,*)
        const float* p3 = p2 + 3 * r1;                        // (1,1,*)

        const f4u a0 = *(const f4u*)p0;  const f2u b0 = *(const f2u*)(p0 + 4);
        const f4u a1 = *(const f4u*)p1;  const f2u b1 = *(const f2u*)(p1 + 4);
        const f4u a2 = *(const f4u*)p2;  const f2u b2 = *(const f2u*)(p2 + 4);
        const f4u a3 = *(const f4u*)p3;  const f2u b3 = *(const f2u*)(p3 + 4);

        const float freq = (float)(1 << l);
        const float wz0  = 1.0f - oz;
        const float wx1 = ox, wx0 = 1.0f - ox;
        const float wy1 = oy, wy0 = 1.0f - oy;

        float sn, cs;
        // a = (v0x v0y v0z v1x), b = (v1y v1z)
        #define PAIR(a, b, WXY)                                                   \
        {                                                                         \
            const float w0 = (WXY) * wz0;                                         \
            const float w1 = (WXY) * oz;                                          \
            __sincosf(a.x * freq, &sn, &cs); acc0 += w0 * sn; acc3 += w0 * cs;    \
            __sincosf(a.y * freq, &sn, &cs); acc1 += w0 * sn; acc4 += w0 * cs;    \
            __sincosf(a.z * freq, &sn, &cs); acc2 += w0 * sn; acc5 += w0 * cs;    \
            __sincosf(a.w * freq, &sn, &cs); acc0 += w1 * sn; acc3 += w1 * cs;    \
            __sincosf(b.x * freq, &sn, &cs); acc1 += w1 * sn; acc4 += w1 * cs;    \
            __sincosf(b.y * freq, &sn, &cs); acc2 += w1 * sn; acc5 += w1 * cs;    \
        }
        PAIR(a0, b0, wx0 * wy0)
        PAIR(a1, b1, wx0 * wy1)
        PAIR(a2, b2, wx1 * wy0)
        PAIR(a3, b3, wx1 * wy1)
        #undef PAIR
    }

    // stage results: row = [x, y, z, l0:6 feats, l1:6 feats, ...]
    {
        float* row = sres[p];
        const int c = 3 + l * 6;
        row[c + 0] = acc0; row[c + 1] = acc1; row[c + 2] = acc2;
        row[c + 3] = acc3; row[c + 4] = acc4; row[c + 5] = acc5;
        if (l == 0) { row[0] = rx; row[1] = ry; row[2] = rz; }
    }
    __syncthreads();

    // coalesced write: 32*51 = 1632 floats = 408 float4 per block (16B aligned)
    if (full_block) {
        const float4* flat4 = (const float4*)&sres[0][0];
        float4* ob4 = (float4*)(out + (size_t)block_base * ROW_F);
        for (int i = tid; i < (PTS_PER_BLOCK * ROW_F) / 4; i += 256)
            ob4[i] = flat4[i];
    } else {
        const float* flat = &sres[0][0];
        float* ob = out + (size_t)block_base * ROW_F;
        const int lim = npts * ROW_F - block_base * ROW_F;
        for (int i = tid; i < PTS_PER_BLOCK * ROW_F; i += 256)
            if (i < lim) ob[i] = flat[i];
    }
}

extern "C" void kernel_launch(void* const* d_in, const int* in_sizes, int n_in,
                              void* d_out, int out_size, void* d_ws, size_t ws_size,
                              hipStream_t stream) {
    const float* xyz           = (const float*)d_in[0];
    const float* data          = (const float*)d_in[1];
    const float* scales        = (const float*)d_in[2];
    const int*   level_offsets = (const int*)d_in[3];
    const float* bounds        = (const float*)d_in[4];
    float* out = (float*)d_out;

    const int npts = in_sizes[0] / 3;
    const int nblocks = (npts + PTS_PER_BLOCK - 1) / PTS_PER_BLOCK;
    dagrid_kernel<<<nblocks, 256, 0, stream>>>(xyz, data, scales, level_offsets,
                                               bounds, out, npts);
}

// Round 4
// 138.945 us; speedup vs baseline: 1.2731x; 1.0231x over previous
//
#include <hip/hip_runtime.h>

#define NLEV 8
#define PTS_PER_BLOCK 32
#define ROW_F 51                 // 3 + 6*NLEV
#define UNITS 256                // (point,level) units per block
#define SLOT 26                  // dwords per unit in spair: 24 data + 2 pad (keeps 8B align)

// 12B load, only 4B-aligned (table is packed float3) -> global_load_dwordx3
typedef float f3u __attribute__((ext_vector_type(3), aligned(4)));

__global__ __launch_bounds__(256) void dagrid_kernel(
    const float* __restrict__ xyz,
    const float* __restrict__ data,
    const float* __restrict__ scales,
    const int*   __restrict__ level_offsets,
    const float* __restrict__ bounds,
    float* __restrict__ out,
    int npts)
{
    __shared__ alignas(16) float sxyz[PTS_PER_BLOCK * 3];
    __shared__ unsigned         saddr[UNITS * 4];      // pair base dword-indices
    __shared__ alignas(16) float spair[UNITS * SLOT];  // gathered pairs
    __shared__ alignas(16) float sres[PTS_PER_BLOCK][ROW_F];

    const int tid = threadIdx.x;
    const int l   = tid & 7;        // level
    const int p   = tid >> 3;       // local point 0..31
    const int block_base = blockIdx.x * PTS_PER_BLOCK;
    const bool full_block = (block_base + PTS_PER_BLOCK <= npts);

    // ---- phase 0: coalesced stage of 32 points' xyz
    if (full_block) {
        if (tid < 24) {
            // block_base*3 floats = blockIdx*384 bytes -> 16B aligned
            ((float4*)sxyz)[tid] = ((const float4*)(xyz + (size_t)block_base * 3))[tid];
        }
    } else if (tid < PTS_PER_BLOCK * 3) {
        const int gi = block_base * 3 + tid;
        sxyz[tid] = (gi < npts * 3) ? xyz[gi] : 0.0f;
    }

    const float scale = scales[l];
    const int   off_l = level_offsets[l];

    const float lox = bounds[0], loy = bounds[1], loz = bounds[2];
    const float hix = bounds[3] - 1e-6f;
    const float hiy = bounds[4] - 1e-6f;
    const float hiz = bounds[5] - 1e-6f;
    const float size = fmaxf(fmaxf(bounds[3] - bounds[0], bounds[4] - bounds[1]),
                             bounds[5] - bounds[2]);
    const float inv_size = 1.0f / size;

    __syncthreads();   // A: sxyz ready

    const int n = block_base + p;
    const bool active = (n < npts);

    const float rx = sxyz[p * 3 + 0];
    const float ry = sxyz[p * 3 + 1];
    const float rz = sxyz[p * 3 + 2];

    // ---- phase 1: per-unit address computation -> saddr
    float ox = 0.f, oy = 0.f, oz = 0.f;
    {
        const float x = fminf(fmaxf(rx, lox), hix);
        const float y = fminf(fmaxf(ry, loy), hiy);
        const float z = fminf(fmaxf(rz, loz), hiz);
        const float xn = (x - lox) * inv_size;
        const float yn = (y - loy) * inv_size;
        const float zn = (z - loz) * inv_size;

        const int r1   = (int)scale + 1;
        const int r1sq = r1 * r1;

        const float fx = xn * scale;
        const float fy = yn * scale;
        const float fz = zn * scale;
        const float bxf = floorf(fx), byf = floorf(fy), bzf = floorf(fz);
        ox = fx - bxf;
        oy = fy - byf;
        oz = fz - bzf;

        const int i000 = (int)bxf * r1sq + (int)byf * r1 + (int)bzf + off_l;
        const unsigned b0 = active ? 3u * (unsigned)i000 : 0u;
        // c: bit1 = cx, bit0 = cy
        saddr[tid * 4 + 0] = b0;
        saddr[tid * 4 + 1] = active ? b0 + 3u * (unsigned)r1 : 0u;
        saddr[tid * 4 + 2] = active ? b0 + 3u * (unsigned)r1sq : 0u;
        saddr[tid * 4 + 3] = active ? b0 + 3u * (unsigned)(r1sq + r1) : 0u;
    }

    __syncthreads();   // B: saddr ready

    // ---- phase 2: cooperative gather. 2 adjacent lanes per 24B pair,
    // each lane one dwordx3 -> contiguous lane addresses -> TA line-merge.
    #pragma unroll
    for (int k = 0; k < 8; ++k) {
        const int m = tid + 256 * k;          // 0..2047 half-pair id
        const int q = m >> 1;                 // pair id 0..1023
        const int h = m & 1;                  // which 12B half
        const unsigned gidx = saddr[q] + 3u * (unsigned)h;
        const f3u v = *(const f3u*)(data + gidx);
        const int u = q >> 2;                 // owning unit
        const int c = q & 3;                  // corner pair
        float* dst = &spair[u * SLOT + c * 6 + 3 * h];
        dst[0] = v.x; dst[1] = v.y; dst[2] = v.z;
    }

    __syncthreads();   // C: spair ready

    // ---- phase 3: compute (reads pairs from LDS)
    float acc0 = 0.f, acc1 = 0.f, acc2 = 0.f, acc3 = 0.f, acc4 = 0.f, acc5 = 0.f;
    if (active) {
        const float freq = (float)(1 << l);
        const float wz0  = 1.0f - oz;
        const float wx1 = ox, wx0 = 1.0f - ox;
        const float wy1 = oy, wy0 = 1.0f - oy;
        const float* up = &spair[tid * SLOT];

        float sn, cs;
        #define PAIRC(c, WXY)                                                     \
        {                                                                         \
            const float w0 = (WXY) * wz0;                                         \
            const float w1 = (WXY) * oz;                                          \
            const float* pv = up + (c) * 6;                                       \
            __sincosf(pv[0] * freq, &sn, &cs); acc0 += w0 * sn; acc3 += w0 * cs;  \
            __sincosf(pv[1] * freq, &sn, &cs); acc1 += w0 * sn; acc4 += w0 * cs;  \
            __sincosf(pv[2] * freq, &sn, &cs); acc2 += w0 * sn; acc5 += w0 * cs;  \
            __sincosf(pv[3] * freq, &sn, &cs); acc0 += w1 * sn; acc3 += w1 * cs;  \
            __sincosf(pv[4] * freq, &sn, &cs); acc1 += w1 * sn; acc4 += w1 * cs;  \
            __sincosf(pv[5] * freq, &sn, &cs); acc2 += w1 * sn; acc5 += w1 * cs;  \
        }
        PAIRC(0, wx0 * wy0)
        PAIRC(1, wx0 * wy1)
        PAIRC(2, wx1 * wy0)
        PAIRC(3, wx1 * wy1)
        #undef PAIRC
    }

    // stage results: row = [x, y, z, l0:6 feats, l1:6 feats, ...]
    {
        float* row = sres[p];
        const int c = 3 + l * 6;
        row[c + 0] = acc0; row[c + 1] = acc1; row[c + 2] = acc2;
        row[c + 3] = acc3; row[c + 4] = acc4; row[c + 5] = acc5;
        if (l == 0) { row[0] = rx; row[1] = ry; row[2] = rz; }
    }
    __syncthreads();   // D: sres ready

    // coalesced write: 32*51 = 1632 floats = 408 float4 per block (16B aligned)
    if (full_block) {
        const float4* flat4 = (const float4*)&sres[0][0];
        float4* ob4 = (float4*)(out + (size_t)block_base * ROW_F);
        for (int i = tid; i < (PTS_PER_BLOCK * ROW_F) / 4; i += 256)
            ob4[i] = flat4[i];
    } else {
        const float* flat = &sres[0][0];
        float* ob = out + (size_t)block_base * ROW_F;
        const int lim = npts * ROW_F - block_base * ROW_F;
        for (int i = tid; i < PTS_PER_BLOCK * ROW_F; i += 256)
            if (i < lim) ob[i] = flat[i];
    }
}

extern "C" void kernel_launch(void* const* d_in, const int* in_sizes, int n_in,
                              void* d_out, int out_size, void* d_ws, size_t ws_size,
                              hipStream_t stream) {
    const float* xyz           = (const float*)d_in[0];
    const float* data          = (const float*)d_in[1];
    const float* scales        = (const float*)d_in[2];
    const int*   level_offsets = (const int*)d_in[3];
    const float* bounds        = (const float*)d_in[4];
    float* out = (float*)d_out;

    const int npts = in_sizes[0] / 3;
    const int nblocks = (npts + PTS_PER_BLOCK - 1) / PTS_PER_BLOCK;
    dagrid_kernel<<<nblocks, 256, 0, stream>>>(xyz, data, scales, level_offsets,
                                               bounds, out, npts);
}